// Round 5
// baseline (363.943 us; speedup 1.0000x reference)
//
#include <hip/hip_runtime.h>
#include <hip/hip_fp16.h>
#include <cmath>

#define HALO 5
#define TSX 32
#define TILE_H 128
#define NSTEP 8          // steady pipeline steps, CH output rows each
#define CH 16
#define RING 42          // 2*CH + 2*HALO: consumer 26 rows + producer 16 rows
#define HSTR 36          // ring row stride in u32 (32 cols + pad, conflict-free)
#define PLANE (RING * HSTR)   // u32 per field-pair plane
#define WIDTH 512
#define HEIGHT 512

struct GW { float g[11]; };

__device__ __forceinline__ uint32_t pk2(float a, float b)
{
    auto h = __builtin_amdgcn_cvt_pkrtz(a, b);   // single v_cvt_pkrtz_f16_f32
    return __builtin_bit_cast(uint32_t, h);
}

__device__ __forceinline__ float ssim2(float mu1, float mu2,
                                       float x2b, float y2b, float xyb)
{
    const float C1 = 1e-4f, C2 = 9e-4f;
    float mu12 = mu1 * mu2;
    float num  = (2.f * mu12 + C1) * (2.f * (xyb - mu12) + C2);
    float den  = (mu1 * mu1 + mu2 * mu2 + C1) *
                 ((x2b - mu1 * mu1) + (y2b - mu2 * mu2) + C2);
    return num * __builtin_amdgcn_rcpf(den);   // ~1 ulp; threshold is 2e-2
}

// H-blur one image row (f32 math) into ring slot `slot` as 4 fp16x2 planes.
// 8 lanes/row (qA 0..7), each lane produces 4 cols x 8 fields.
template<bool CX, bool CY>
__device__ __forceinline__ void hblur_row(
    const float* __restrict__ rowf, const float* __restrict__ rowa,
    const float* __restrict__ rowb, bool yok, int gx0, int slot, int qA,
    uint32_t (* __restrict__ hb)[PLANE], const GW& gw)
{
    float acc[4][8];
    #pragma unroll
    for (int jj = 0; jj < 4; ++jj)
        #pragma unroll
        for (int q = 0; q < 8; ++q) acc[jj][q] = 0.f;

    #pragma unroll
    for (int k = 0; k < 5; ++k) {
        const int g = gx0 + 4 * k;
        float4 vf, va, vb;
        if (CX || CY) {
            bool ok = true;
            if (CY) ok = yok;
            if (CX) ok = ok && ((unsigned)g <= (unsigned)(WIDTH - 4));
            vf = ok ? *(const float4*)(rowf + g) : make_float4(0,0,0,0);
            va = ok ? *(const float4*)(rowa + g) : make_float4(0,0,0,0);
            vb = ok ? *(const float4*)(rowb + g) : make_float4(0,0,0,0);
        } else {
            vf = *(const float4*)(rowf + g);
            va = *(const float4*)(rowa + g);
            vb = *(const float4*)(rowb + g);
        }
        const float fs[4] = { vf.x, vf.y, vf.z, vf.w };
        const float as[4] = { va.x, va.y, va.z, va.w };
        const float bs[4] = { vb.x, vb.y, vb.z, vb.w };
        #pragma unroll
        for (int cc = 0; cc < 4; ++cc) {
            const int tt = 4 * k + cc - 3;    // window col 0..13
            if (tt < 0 || tt > 13) continue;  // static prune
            const float f = fs[cc], a = as[cc], b = bs[cc];
            float p[8];
            p[0] = f; p[1] = a; p[2] = b;
            p[3] = f * f; p[4] = a * a; p[5] = b * b;
            p[6] = f * a; p[7] = f * b;
            #pragma unroll
            for (int jj = 0; jj < 4; ++jj) {
                const int u = tt - jj;        // tap index
                if (u >= 0 && u <= 10) {
                    const float w = gw.g[u];
                    #pragma unroll
                    for (int q = 0; q < 8; ++q)
                        acc[jj][q] = fmaf(w, p[q], acc[jj][q]);
                }
            }
        }
    }
    // pack field pairs (2p, 2p+1) -> plane p, cols 4qA..4qA+3, one b128/plane
    #pragma unroll
    for (int p = 0; p < 4; ++p) {
        uint4 v = make_uint4(pk2(acc[0][2*p], acc[0][2*p+1]),
                             pk2(acc[1][2*p], acc[1][2*p+1]),
                             pk2(acc[2][2*p], acc[2][2*p+1]),
                             pk2(acc[3][2*p], acc[3][2*p+1]));
        *(uint4*)(&hb[p][slot * HSTR + 4 * qA]) = v;
    }
}

// Producer/consumer pipeline: waves 0-1 H-blur chunk s+1 while waves 2-3
// V-blur+SSIM chunk s. Consumer reads ring rows [16s,16s+26), producer writes
// [16s+26,16s+42) — complementary halves of the 42-row ring, one barrier/step.
template<bool CX, bool CY>
__device__ __forceinline__ float tile_compute(
    const float* __restrict__ fI, const float* __restrict__ aI,
    const float* __restrict__ bI, uint32_t (* __restrict__ hb)[PLANE],
    const GW& gw, int tid, int x0, int y0, size_t pbase)
{
    const int rA  = tid >> 3;            // producer row-slot
    const int qA  = tid & 7;
    const int gx0 = x0 + 4 * qA - 8;     // first loaded global col (5 quads)
    const int jB  = tid & 31;            // consumer col
    const int rgB = (tid >> 5) & 3;      // consumer row-group 0..3

    __half2 wh[11];                      // broadcast fp16 weights (static idx)
    #pragma unroll
    for (int i = 0; i < 11; ++i) wh[i] = __float2half2_rn(gw.g[i]);

    float part = 0.f;

    // ---- prologue: all 256 threads prime ring rows 0..25 ----
    if (rA < 26) {
        const int yy = y0 - HALO + rA;
        const bool yok = CY ? ((unsigned)yy < (unsigned)HEIGHT) : true;
        hblur_row<CX, CY>(fI + pbase + (size_t)yy * WIDTH,
                          aI + pbase + (size_t)yy * WIDTH,
                          bI + pbase + (size_t)yy * WIDTH,
                          yok, gx0, rA, qA, hb, gw);
    }
    __syncthreads();

    #pragma unroll 1
    for (int s = 0; s < NSTEP; ++s) {
        if (tid < 128) {
            // ---- producer: H-blur the 16 new rows for chunk s+1 ----
            if (s < NSTEP - 1) {
                const int t = CH * s + RING - CH + rA;   // 16s+26+rA, <=137
                int slot = t;
                slot -= (slot >= RING) ? RING : 0;
                slot -= (slot >= RING) ? RING : 0;
                slot -= (slot >= RING) ? RING : 0;
                const int yy = y0 - HALO + t;
                const bool yok = CY ? ((unsigned)yy < (unsigned)HEIGHT) : true;
                hblur_row<CX, CY>(fI + pbase + (size_t)yy * WIDTH,
                                  aI + pbase + (size_t)yy * WIDTH,
                                  bI + pbase + (size_t)yy * WIDTH,
                                  yok, gx0, slot, qA, hb, gw);
            }
        } else {
            // ---- consumer: packed-fp16 vertical blur + SSIM ----
            int sb = CH * s + 4 * rgB;    // first input row (rel y0-5), <=124
            sb -= (sb >= RING) ? RING : 0;
            sb -= (sb >= RING) ? RING : 0;
            __half2 acc2[4][4];           // [ri][plane], static-indexed only
            #pragma unroll
            for (int ri = 0; ri < 4; ++ri)
                #pragma unroll
                for (int p = 0; p < 4; ++p)
                    acc2[ri][p] = __float2half2_rn(0.f);
            #pragma unroll
            for (int k = 0; k < 14; ++k) {
                int t = sb + k;
                t -= (t >= RING) ? RING : 0;
                const uint32_t* hp = &hb[0][t * HSTR + jB];
                __half2 hv[4];
                #pragma unroll
                for (int p = 0; p < 4; ++p)
                    hv[p] = __builtin_bit_cast(__half2, hp[p * PLANE]);
                #pragma unroll
                for (int ri = 0; ri < 4; ++ri) {
                    const int u = k - ri;
                    if (u >= 0 && u <= 10) {
                        #pragma unroll
                        for (int p = 0; p < 4; ++p)
                            acc2[ri][p] = __hfma2(wh[u], hv[p], acc2[ri][p]);
                    }
                }
            }
            #pragma unroll
            for (int ri = 0; ri < 4; ++ri) {
                // planes: 0=(F,A) 1=(B,F2) 2=(A2,B2) 3=(FA,FB)
                const float F  = __low2float (acc2[ri][0]);
                const float A  = __high2float(acc2[ri][0]);
                const float B  = __low2float (acc2[ri][1]);
                const float F2 = __high2float(acc2[ri][1]);
                const float A2 = __low2float (acc2[ri][2]);
                const float B2 = __high2float(acc2[ri][2]);
                const float FA = __low2float (acc2[ri][3]);
                const float FB = __high2float(acc2[ri][3]);
                part += ssim2(F, A, F2, A2, FA);
                part += ssim2(F, B, F2, B2, FB);
            }
        }
        __syncthreads();
    }
    return part;
}

__global__ __launch_bounds__(256, 6)
void ssim_tile(const float* __restrict__ fI, const float* __restrict__ aI,
               const float* __restrict__ bI, float* __restrict__ bsum,
               GW gw)
{
    __shared__ __align__(16) uint32_t hb[4][PLANE];   // 24.2 KB -> 6 blocks/CU
    __shared__ float red[4];

    const int tid = threadIdx.x;
    const int x0 = blockIdx.x * TSX;
    const int y0 = blockIdx.y * TILE_H;
    const size_t pbase = (size_t)blockIdx.z * (size_t)(WIDTH * HEIGHT);

    const bool ex = (blockIdx.x == 0) || (blockIdx.x == gridDim.x - 1);
    const bool ey = (blockIdx.y == 0) || (blockIdx.y == gridDim.y - 1);

    float part;
    if (!ex && !ey)
        part = tile_compute<false, false>(fI, aI, bI, hb, gw, tid, x0, y0, pbase);
    else if (!ex)
        part = tile_compute<false, true >(fI, aI, bI, hb, gw, tid, x0, y0, pbase);
    else if (!ey)
        part = tile_compute<true,  false>(fI, aI, bI, hb, gw, tid, x0, y0, pbase);
    else
        part = tile_compute<true,  true >(fI, aI, bI, hb, gw, tid, x0, y0, pbase);

    // ---- reduction -> per-block partial (no atomics) ----
    #pragma unroll
    for (int off = 32; off > 0; off >>= 1) part += __shfl_down(part, off);
    if ((tid & 63) == 0) red[tid >> 6] = part;
    __syncthreads();
    if (tid == 0) {
        int bid = blockIdx.x + gridDim.x * (blockIdx.y + gridDim.y * blockIdx.z);
        bsum[bid] = red[0] + red[1] + red[2] + red[3];
    }
}

__global__ __launch_bounds__(256)
void ssim_final(const float* __restrict__ bsum, float* __restrict__ out,
                int nb, float invTwoN)
{
    __shared__ float sred[4];
    float s = 0.f;
    for (int i = threadIdx.x; i < nb; i += 256) s += bsum[i];
    #pragma unroll
    for (int off = 32; off > 0; off >>= 1) s += __shfl_down(s, off);
    if ((threadIdx.x & 63) == 0) sred[threadIdx.x >> 6] = s;
    __syncthreads();
    if (threadIdx.x == 0)
        out[0] = 1.f - (sred[0] + sred[1] + sred[2] + sred[3]) * invTwoN;
}

extern "C" void kernel_launch(void* const* d_in, const int* in_sizes, int n_in,
                              void* d_out, int out_size, void* d_ws, size_t ws_size,
                              hipStream_t stream)
{
    const float* f  = (const float*)d_in[0];
    const float* s1 = (const float*)d_in[1];
    const float* s2 = (const float*)d_in[2];
    float* out  = (float*)d_out;
    float* bsum = (float*)d_ws;          // 3072 floats = 12 KB scratch

    const int N = in_sizes[0];           // 48 * 512 * 512
    const int planes = N / (WIDTH * HEIGHT);

    GW gw;
    double gd[11], gs = 0.0;
    for (int i = 0; i < 11; ++i) {
        double d = (double)(i - 5);
        gd[i] = exp(-(d * d) / 4.5);     // 2*sigma^2 = 4.5
        gs += gd[i];
    }
    for (int i = 0; i < 11; ++i) gw.g[i] = (float)(gd[i] / gs);

    dim3 grid(WIDTH / TSX, HEIGHT / TILE_H, planes);
    const int nb = (WIDTH / TSX) * (HEIGHT / TILE_H) * planes;
    ssim_tile<<<grid, dim3(256), 0, stream>>>(f, s1, s2, bsum, gw);
    ssim_final<<<1, dim3(256), 0, stream>>>(bsum, out, nb, 0.5f / (float)N);
}

// Round 6
// 264.232 us; speedup vs baseline: 1.3774x; 1.3774x over previous
//
#include <hip/hip_runtime.h>
#include <hip/hip_fp16.h>
#include <cmath>

#define HALO 5
#define TSX 32
#define TILE_H 128
#define NSTEP 8          // steady pipeline steps, CH output rows each
#define CH 16
#define RING 42          // 2*CH + 2*HALO: consumer 26 rows + producer 16 rows
#define HSTR 36          // ring row stride in u32 (32 cols + pad, conflict-free)
#define PLANE (RING * HSTR)   // u32 per field-pair plane
#define WIDTH 512
#define HEIGHT 512

struct GW { float g[11]; };

__device__ __forceinline__ uint32_t pk2(float a, float b)
{
    auto h = __builtin_amdgcn_cvt_pkrtz(a, b);   // single v_cvt_pkrtz_f16_f32
    return __builtin_bit_cast(uint32_t, h);
}

__device__ __forceinline__ float ssim2(float mu1, float mu2,
                                       float x2b, float y2b, float xyb)
{
    const float C1 = 1e-4f, C2 = 9e-4f;
    float mu12 = mu1 * mu2;
    float num  = (2.f * mu12 + C1) * (2.f * (xyb - mu12) + C2);
    float den  = (mu1 * mu1 + mu2 * mu2 + C1) *
                 ((x2b - mu1 * mu1) + (y2b - mu2 * mu2) + C2);
    return num * __builtin_amdgcn_rcpf(den);   // ~1 ulp; threshold is 2e-2
}

// H-blur one image row (f32 math) into ring slot `slot` as 4 fp16x2 planes.
// 8 lanes/row (qA 0..7), each lane produces 4 cols x 8 fields.
template<bool CX, bool CY>
__device__ __forceinline__ void hblur_row(
    const float* __restrict__ rowf, const float* __restrict__ rowa,
    const float* __restrict__ rowb, bool yok, int gx0, int slot, int qA,
    uint32_t (* __restrict__ hb)[PLANE], const GW& gw)
{
    float acc[4][8];
    #pragma unroll
    for (int jj = 0; jj < 4; ++jj)
        #pragma unroll
        for (int q = 0; q < 8; ++q) acc[jj][q] = 0.f;

    #pragma unroll
    for (int k = 0; k < 5; ++k) {
        const int g = gx0 + 4 * k;
        float4 vf, va, vb;
        if (CX || CY) {
            bool ok = true;
            if (CY) ok = yok;
            if (CX) ok = ok && ((unsigned)g <= (unsigned)(WIDTH - 4));
            vf = ok ? *(const float4*)(rowf + g) : make_float4(0,0,0,0);
            va = ok ? *(const float4*)(rowa + g) : make_float4(0,0,0,0);
            vb = ok ? *(const float4*)(rowb + g) : make_float4(0,0,0,0);
        } else {
            vf = *(const float4*)(rowf + g);
            va = *(const float4*)(rowa + g);
            vb = *(const float4*)(rowb + g);
        }
        const float fs[4] = { vf.x, vf.y, vf.z, vf.w };
        const float as[4] = { va.x, va.y, va.z, va.w };
        const float bs[4] = { vb.x, vb.y, vb.z, vb.w };
        #pragma unroll
        for (int cc = 0; cc < 4; ++cc) {
            const int tt = 4 * k + cc - 3;    // window col 0..13
            if (tt < 0 || tt > 13) continue;  // static prune
            const float f = fs[cc], a = as[cc], b = bs[cc];
            float p[8];
            p[0] = f; p[1] = a; p[2] = b;
            p[3] = f * f; p[4] = a * a; p[5] = b * b;
            p[6] = f * a; p[7] = f * b;
            #pragma unroll
            for (int jj = 0; jj < 4; ++jj) {
                const int u = tt - jj;        // tap index
                if (u >= 0 && u <= 10) {
                    const float w = gw.g[u];
                    #pragma unroll
                    for (int q = 0; q < 8; ++q)
                        acc[jj][q] = fmaf(w, p[q], acc[jj][q]);
                }
            }
        }
    }
    // pack field pairs (2p, 2p+1) -> plane p, cols 4qA..4qA+3, one b128/plane
    #pragma unroll
    for (int p = 0; p < 4; ++p) {
        uint4 v = make_uint4(pk2(acc[0][2*p], acc[0][2*p+1]),
                             pk2(acc[1][2*p], acc[1][2*p+1]),
                             pk2(acc[2][2*p], acc[2][2*p+1]),
                             pk2(acc[3][2*p], acc[3][2*p+1]));
        *(uint4*)(&hb[p][slot * HSTR + 4 * qA]) = v;
    }
}

// Producer/consumer pipeline: waves 0-1 H-blur chunk s+1 while waves 2-3
// V-blur+SSIM chunk s. Consumer reads ring rows [16s,16s+26), producer writes
// [16s+26,16s+42) — complementary halves of the 42-row ring, one barrier/step.
template<bool CX, bool CY>
__device__ __forceinline__ float tile_compute(
    const float* __restrict__ fI, const float* __restrict__ aI,
    const float* __restrict__ bI, uint32_t (* __restrict__ hb)[PLANE],
    const GW& gw, int tid, int x0, int y0, size_t pbase)
{
    const int rA  = tid >> 3;            // producer row-slot
    const int qA  = tid & 7;
    const int gx0 = x0 + 4 * qA - 8;     // first loaded global col (5 quads)
    const int jB  = tid & 31;            // consumer col
    const int rgB = (tid >> 5) & 3;      // consumer row-group 0..3

    __half2 wh[11];                      // broadcast fp16 weights (static idx)
    #pragma unroll
    for (int i = 0; i < 11; ++i) wh[i] = __float2half2_rn(gw.g[i]);

    float part = 0.f;

    // ---- prologue: all 256 threads prime ring rows 0..25 ----
    if (rA < 26) {
        const int yy = y0 - HALO + rA;
        const bool yok = CY ? ((unsigned)yy < (unsigned)HEIGHT) : true;
        hblur_row<CX, CY>(fI + pbase + (size_t)yy * WIDTH,
                          aI + pbase + (size_t)yy * WIDTH,
                          bI + pbase + (size_t)yy * WIDTH,
                          yok, gx0, rA, qA, hb, gw);
    }
    __syncthreads();

    #pragma unroll 1
    for (int s = 0; s < NSTEP; ++s) {
        if (tid < 128) {
            // ---- producer: H-blur the 16 new rows for chunk s+1 ----
            if (s < NSTEP - 1) {
                const int t = CH * s + RING - CH + rA;   // 16s+26+rA, <=137
                int slot = t;
                slot -= (slot >= RING) ? RING : 0;
                slot -= (slot >= RING) ? RING : 0;
                slot -= (slot >= RING) ? RING : 0;
                const int yy = y0 - HALO + t;
                const bool yok = CY ? ((unsigned)yy < (unsigned)HEIGHT) : true;
                hblur_row<CX, CY>(fI + pbase + (size_t)yy * WIDTH,
                                  aI + pbase + (size_t)yy * WIDTH,
                                  bI + pbase + (size_t)yy * WIDTH,
                                  yok, gx0, slot, qA, hb, gw);
            }
        } else {
            // ---- consumer: packed-fp16 vertical blur + SSIM ----
            int sb = CH * s + 4 * rgB;    // first input row (rel y0-5), <=124
            sb -= (sb >= RING) ? RING : 0;
            sb -= (sb >= RING) ? RING : 0;
            __half2 acc2[4][4];           // [ri][plane], static-indexed only
            #pragma unroll
            for (int ri = 0; ri < 4; ++ri)
                #pragma unroll
                for (int p = 0; p < 4; ++p)
                    acc2[ri][p] = __float2half2_rn(0.f);
            #pragma unroll
            for (int k = 0; k < 14; ++k) {
                int t = sb + k;
                t -= (t >= RING) ? RING : 0;
                const uint32_t* hp = &hb[0][t * HSTR + jB];
                __half2 hv[4];
                #pragma unroll
                for (int p = 0; p < 4; ++p)
                    hv[p] = __builtin_bit_cast(__half2, hp[p * PLANE]);
                #pragma unroll
                for (int ri = 0; ri < 4; ++ri) {
                    const int u = k - ri;
                    if (u >= 0 && u <= 10) {
                        #pragma unroll
                        for (int p = 0; p < 4; ++p)
                            acc2[ri][p] = __hfma2(wh[u], hv[p], acc2[ri][p]);
                    }
                }
            }
            #pragma unroll
            for (int ri = 0; ri < 4; ++ri) {
                // planes: 0=(F,A) 1=(B,F2) 2=(A2,B2) 3=(FA,FB)
                const float F  = __low2float (acc2[ri][0]);
                const float A  = __high2float(acc2[ri][0]);
                const float B  = __low2float (acc2[ri][1]);
                const float F2 = __high2float(acc2[ri][1]);
                const float A2 = __low2float (acc2[ri][2]);
                const float B2 = __high2float(acc2[ri][2]);
                const float FA = __low2float (acc2[ri][3]);
                const float FB = __high2float(acc2[ri][3]);
                part += ssim2(F, A, F2, A2, FA);
                part += ssim2(F, B, F2, B2, FB);
            }
        }
        __syncthreads();
    }
    return part;
}

// (256,4): waves/EU floor -> VGPR cap 128. Round-5's (256,6) capped VGPR at
// ~85; body needs ~87 -> allocator spilled ~300 MB of scratch (VGPR 40,
// WRITE_SIZE 290 MB). LDS (24.2 KB) still permits 6 blocks/CU at runtime if
// the allocator lands <=85 regs.
__global__ __launch_bounds__(256, 4)
void ssim_tile(const float* __restrict__ fI, const float* __restrict__ aI,
               const float* __restrict__ bI, float* __restrict__ bsum,
               GW gw)
{
    __shared__ __align__(16) uint32_t hb[4][PLANE];   // 24.2 KB
    __shared__ float red[4];

    const int tid = threadIdx.x;
    const int x0 = blockIdx.x * TSX;
    const int y0 = blockIdx.y * TILE_H;
    const size_t pbase = (size_t)blockIdx.z * (size_t)(WIDTH * HEIGHT);

    const bool ex = (blockIdx.x == 0) || (blockIdx.x == gridDim.x - 1);
    const bool ey = (blockIdx.y == 0) || (blockIdx.y == gridDim.y - 1);

    float part;
    if (!ex && !ey)
        part = tile_compute<false, false>(fI, aI, bI, hb, gw, tid, x0, y0, pbase);
    else if (!ex)
        part = tile_compute<false, true >(fI, aI, bI, hb, gw, tid, x0, y0, pbase);
    else if (!ey)
        part = tile_compute<true,  false>(fI, aI, bI, hb, gw, tid, x0, y0, pbase);
    else
        part = tile_compute<true,  true >(fI, aI, bI, hb, gw, tid, x0, y0, pbase);

    // ---- reduction -> per-block partial (no atomics) ----
    #pragma unroll
    for (int off = 32; off > 0; off >>= 1) part += __shfl_down(part, off);
    if ((tid & 63) == 0) red[tid >> 6] = part;
    __syncthreads();
    if (tid == 0) {
        int bid = blockIdx.x + gridDim.x * (blockIdx.y + gridDim.y * blockIdx.z);
        bsum[bid] = red[0] + red[1] + red[2] + red[3];
    }
}

__global__ __launch_bounds__(256)
void ssim_final(const float* __restrict__ bsum, float* __restrict__ out,
                int nb, float invTwoN)
{
    __shared__ float sred[4];
    float s = 0.f;
    for (int i = threadIdx.x; i < nb; i += 256) s += bsum[i];
    #pragma unroll
    for (int off = 32; off > 0; off >>= 1) s += __shfl_down(s, off);
    if ((threadIdx.x & 63) == 0) sred[threadIdx.x >> 6] = s;
    __syncthreads();
    if (threadIdx.x == 0)
        out[0] = 1.f - (sred[0] + sred[1] + sred[2] + sred[3]) * invTwoN;
}

extern "C" void kernel_launch(void* const* d_in, const int* in_sizes, int n_in,
                              void* d_out, int out_size, void* d_ws, size_t ws_size,
                              hipStream_t stream)
{
    const float* f  = (const float*)d_in[0];
    const float* s1 = (const float*)d_in[1];
    const float* s2 = (const float*)d_in[2];
    float* out  = (float*)d_out;
    float* bsum = (float*)d_ws;          // 3072 floats = 12 KB scratch

    const int N = in_sizes[0];           // 48 * 512 * 512
    const int planes = N / (WIDTH * HEIGHT);

    GW gw;
    double gd[11], gs = 0.0;
    for (int i = 0; i < 11; ++i) {
        double d = (double)(i - 5);
        gd[i] = exp(-(d * d) / 4.5);     // 2*sigma^2 = 4.5
        gs += gd[i];
    }
    for (int i = 0; i < 11; ++i) gw.g[i] = (float)(gd[i] / gs);

    dim3 grid(WIDTH / TSX, HEIGHT / TILE_H, planes);
    const int nb = (WIDTH / TSX) * (HEIGHT / TILE_H) * planes;
    ssim_tile<<<grid, dim3(256), 0, stream>>>(f, s1, s2, bsum, gw);
    ssim_final<<<1, dim3(256), 0, stream>>>(bsum, out, nb, 0.5f / (float)N);
}

// Round 7
// 220.618 us; speedup vs baseline: 1.6497x; 1.1977x over previous
//
#include <hip/hip_runtime.h>
#include <hip/hip_fp16.h>
#include <cmath>
#include <cstring>

#define HALO 5
#define TSX 32
#define TILE_H 128
#define NCHUNK 4
#define CH 32            // output rows per chunk; 32 rows x 8 quads = 256 thr
#define RING 42          // CH + 2*HALO rows live in LDS ring
#define HSTR 36          // ring row stride in u32 (32 cols + pad, conflict-free)
#define PLANE (RING * HSTR)   // u32 per field-pair plane
#define WIDTH 512
#define HEIGHT 512

// f32 weights for phase A (consumed from SGPRs) + host-packed half2 weights
// for phase B (consumed from SGPRs -> no VGPR table; round-6's wh[11] VGPR
// table tipped the allocator into spilling).
struct GW { float g[11]; uint32_t wpk[11]; };

__device__ __forceinline__ uint32_t pk2(float a, float b)
{
    auto h = __builtin_amdgcn_cvt_pkrtz(a, b);   // single v_cvt_pkrtz_f16_f32
    return __builtin_bit_cast(uint32_t, h);
}

__device__ __forceinline__ float ssim2(float mu1, float mu2,
                                       float x2b, float y2b, float xyb)
{
    const float C1 = 1e-4f, C2 = 9e-4f;
    float mu12 = mu1 * mu2;
    float num  = (2.f * mu12 + C1) * (2.f * (xyb - mu12) + C2);
    float den  = (mu1 * mu1 + mu2 * mu2 + C1) *
                 ((x2b - mu1 * mu1) + (y2b - mu2 * mu2) + C2);
    return num * __builtin_amdgcn_rcpf(den);   // ~1 ulp; threshold is 2e-2
}

// H-blur one image row (f32 math) into ring slot `slot` as 4 fp16x2 planes.
// 8 lanes/row (qA 0..7), each lane produces 4 cols x 8 fields. Proven
// spill-free body — keep static, never wrap in dynamic-trip loops.
template<bool CX, bool CY>
__device__ __forceinline__ void hblur_row(
    const float* __restrict__ rowf, const float* __restrict__ rowa,
    const float* __restrict__ rowb, bool yok, int gx0, int slot, int qA,
    uint32_t (* __restrict__ hb)[PLANE], const GW& gw)
{
    float acc[4][8];
    #pragma unroll
    for (int jj = 0; jj < 4; ++jj)
        #pragma unroll
        for (int q = 0; q < 8; ++q) acc[jj][q] = 0.f;

    #pragma unroll
    for (int k = 0; k < 5; ++k) {
        const int g = gx0 + 4 * k;
        float4 vf, va, vb;
        if (CX || CY) {
            bool ok = true;
            if (CY) ok = yok;
            if (CX) ok = ok && ((unsigned)g <= (unsigned)(WIDTH - 4));
            vf = ok ? *(const float4*)(rowf + g) : make_float4(0,0,0,0);
            va = ok ? *(const float4*)(rowa + g) : make_float4(0,0,0,0);
            vb = ok ? *(const float4*)(rowb + g) : make_float4(0,0,0,0);
        } else {
            vf = *(const float4*)(rowf + g);
            va = *(const float4*)(rowa + g);
            vb = *(const float4*)(rowb + g);
        }
        const float fs[4] = { vf.x, vf.y, vf.z, vf.w };
        const float as[4] = { va.x, va.y, va.z, va.w };
        const float bs[4] = { vb.x, vb.y, vb.z, vb.w };
        #pragma unroll
        for (int cc = 0; cc < 4; ++cc) {
            const int tt = 4 * k + cc - 3;    // window col 0..13
            if (tt < 0 || tt > 13) continue;  // static prune
            const float f = fs[cc], a = as[cc], b = bs[cc];
            float p[8];
            p[0] = f; p[1] = a; p[2] = b;
            p[3] = f * f; p[4] = a * a; p[5] = b * b;
            p[6] = f * a; p[7] = f * b;
            #pragma unroll
            for (int jj = 0; jj < 4; ++jj) {
                const int u = tt - jj;        // tap index
                if (u >= 0 && u <= 10) {
                    const float w = gw.g[u];
                    #pragma unroll
                    for (int q = 0; q < 8; ++q)
                        acc[jj][q] = fmaf(w, p[q], acc[jj][q]);
                }
            }
        }
    }
    // pack field pairs (2p, 2p+1) -> plane p, cols 4qA..4qA+3, one b128/plane
    #pragma unroll
    for (int p = 0; p < 4; ++p) {
        uint4 v = make_uint4(pk2(acc[0][2*p], acc[0][2*p+1]),
                             pk2(acc[1][2*p], acc[1][2*p+1]),
                             pk2(acc[2][2*p], acc[2][2*p+1]),
                             pk2(acc[3][2*p], acc[3][2*p+1]));
        *(uint4*)(&hb[p][slot * HSTR + 4 * qA]) = v;
    }
}

// Phase-alternating, ALL 256 threads active in BOTH phases (the 4:1 A:B work
// ratio makes wave-specialization structurally <=62% utilized — measured
// rounds 3/6; alternation has no such cap).
template<bool CX, bool CY>
__device__ __forceinline__ float tile_compute(
    const float* __restrict__ fI, const float* __restrict__ aI,
    const float* __restrict__ bI, uint32_t (* __restrict__ hb)[PLANE],
    const GW& gw, int tid, int x0, int y0, size_t pbase)
{
    const int rA  = tid >> 3;            // phase A row 0..31
    const int qA  = tid & 7;
    const int gx0 = x0 + 4 * qA - 8;     // first loaded global col (5 quads)
    const int jB  = tid & 31;            // phase B col
    const int rgB = tid >> 5;            // phase B row-group 0..7 (4 rows each)

    float part = 0.f;

    // ---- prologue: prime ring rows 0..41 (two STATIC calls, no dyn loop) ----
    {
        const int yy = y0 - HALO + rA;
        const bool yok = CY ? ((unsigned)yy < (unsigned)HEIGHT) : true;
        hblur_row<CX, CY>(fI + pbase + (size_t)yy * WIDTH,
                          aI + pbase + (size_t)yy * WIDTH,
                          bI + pbase + (size_t)yy * WIDTH,
                          yok, gx0, rA, qA, hb, gw);
    }
    if (rA < 10) {
        const int t  = 32 + rA;
        const int yy = y0 - HALO + t;
        const bool yok = CY ? ((unsigned)yy < (unsigned)HEIGHT) : true;
        hblur_row<CX, CY>(fI + pbase + (size_t)yy * WIDTH,
                          aI + pbase + (size_t)yy * WIDTH,
                          bI + pbase + (size_t)yy * WIDTH,
                          yok, gx0, t, qA, hb, gw);
    }
    __syncthreads();

    #pragma unroll 1
    for (int c = 0; c < NCHUNK; ++c) {
        if (c) {
            // ---- phase A: 32 new rows [32c+10, 32c+42) for chunk c ----
            const int t = CH * c + 10 + rA;        // 42..137
            int slot = t;
            slot -= (slot >= RING) ? RING : 0;
            slot -= (slot >= RING) ? RING : 0;
            slot -= (slot >= RING) ? RING : 0;
            const int yy = y0 - HALO + t;
            const bool yok = CY ? ((unsigned)yy < (unsigned)HEIGHT) : true;
            hblur_row<CX, CY>(fI + pbase + (size_t)yy * WIDTH,
                              aI + pbase + (size_t)yy * WIDTH,
                              bI + pbase + (size_t)yy * WIDTH,
                              yok, gx0, slot, qA, hb, gw);
            __syncthreads();
        }

        // ---- phase B: packed-fp16 vertical blur + SSIM, 32 rows ----
        int sb = CH * c + 4 * rgB;        // <=124
        sb -= (sb >= RING) ? RING : 0;
        sb -= (sb >= RING) ? RING : 0;
        __half2 acc2[4][4];               // [ri][plane], static-indexed only
        #pragma unroll
        for (int ri = 0; ri < 4; ++ri)
            #pragma unroll
            for (int p = 0; p < 4; ++p)
                acc2[ri][p] = __float2half2_rn(0.f);
        #pragma unroll
        for (int k = 0; k < 14; ++k) {
            int t = sb + k;
            t -= (t >= RING) ? RING : 0;
            const uint32_t* hp = &hb[0][t * HSTR + jB];
            __half2 hv[4];
            #pragma unroll
            for (int p = 0; p < 4; ++p)
                hv[p] = __builtin_bit_cast(__half2, hp[p * PLANE]);
            #pragma unroll
            for (int ri = 0; ri < 4; ++ri) {
                const int u = k - ri;
                if (u >= 0 && u <= 10) {
                    // u is compile-time -> gw.wpk[u] stays in SGPRs
                    const __half2 w = __builtin_bit_cast(__half2, gw.wpk[u]);
                    #pragma unroll
                    for (int p = 0; p < 4; ++p)
                        acc2[ri][p] = __hfma2(w, hv[p], acc2[ri][p]);
                }
            }
        }
        #pragma unroll
        for (int ri = 0; ri < 4; ++ri) {
            // planes: 0=(F,A) 1=(B,F2) 2=(A2,B2) 3=(FA,FB)
            const float F  = __low2float (acc2[ri][0]);
            const float A  = __high2float(acc2[ri][0]);
            const float B  = __low2float (acc2[ri][1]);
            const float F2 = __high2float(acc2[ri][1]);
            const float A2 = __low2float (acc2[ri][2]);
            const float B2 = __high2float(acc2[ri][2]);
            const float FA = __low2float (acc2[ri][3]);
            const float FB = __high2float(acc2[ri][3]);
            part += ssim2(F, A, F2, A2, FA);
            part += ssim2(F, B, F2, B2, FB);
        }
        __syncthreads();
    }
    return part;
}

// (256,3): the exact bound that produced 76-VGPR spill-free code for this
// body family (round 3). (256,6) capped at 85 -> 290 MB spill; (256,4) the
// allocator still chose 64+spill. Do not tighten.
__global__ __launch_bounds__(256, 3)
void ssim_tile(const float* __restrict__ fI, const float* __restrict__ aI,
               const float* __restrict__ bI, float* __restrict__ bsum,
               GW gw)
{
    __shared__ __align__(16) uint32_t hb[4][PLANE];   // 24.2 KB
    __shared__ float red[4];

    const int tid = threadIdx.x;
    const int x0 = blockIdx.x * TSX;
    const int y0 = blockIdx.y * TILE_H;
    const size_t pbase = (size_t)blockIdx.z * (size_t)(WIDTH * HEIGHT);

    const bool ex = (blockIdx.x == 0) || (blockIdx.x == gridDim.x - 1);
    const bool ey = (blockIdx.y == 0) || (blockIdx.y == gridDim.y - 1);

    float part;
    if (!ex && !ey)
        part = tile_compute<false, false>(fI, aI, bI, hb, gw, tid, x0, y0, pbase);
    else if (!ex)
        part = tile_compute<false, true >(fI, aI, bI, hb, gw, tid, x0, y0, pbase);
    else if (!ey)
        part = tile_compute<true,  false>(fI, aI, bI, hb, gw, tid, x0, y0, pbase);
    else
        part = tile_compute<true,  true >(fI, aI, bI, hb, gw, tid, x0, y0, pbase);

    // ---- reduction -> per-block partial (no atomics) ----
    #pragma unroll
    for (int off = 32; off > 0; off >>= 1) part += __shfl_down(part, off);
    if ((tid & 63) == 0) red[tid >> 6] = part;
    __syncthreads();
    if (tid == 0) {
        int bid = blockIdx.x + gridDim.x * (blockIdx.y + gridDim.y * blockIdx.z);
        bsum[bid] = red[0] + red[1] + red[2] + red[3];
    }
}

__global__ __launch_bounds__(256)
void ssim_final(const float* __restrict__ bsum, float* __restrict__ out,
                int nb, float invTwoN)
{
    __shared__ float sred[4];
    float s = 0.f;
    for (int i = threadIdx.x; i < nb; i += 256) s += bsum[i];
    #pragma unroll
    for (int off = 32; off > 0; off >>= 1) s += __shfl_down(s, off);
    if ((threadIdx.x & 63) == 0) sred[threadIdx.x >> 6] = s;
    __syncthreads();
    if (threadIdx.x == 0)
        out[0] = 1.f - (sred[0] + sred[1] + sred[2] + sred[3]) * invTwoN;
}

// host-side float->half (RNE); weights are small positive normals
static uint16_t f2h(float f)
{
    uint32_t x; std::memcpy(&x, &f, 4);
    uint32_t s = (x >> 16) & 0x8000u;
    int      e = (int)((x >> 23) & 0xff) - 127 + 15;
    uint32_t m = x & 0x007fffffu;
    uint32_t base = ((uint32_t)e << 10) | (m >> 13);
    uint32_t rem  = m & 0x1fffu;
    if (rem > 0x1000u || (rem == 0x1000u && (base & 1u))) base++;
    return (uint16_t)(s | base);
}

extern "C" void kernel_launch(void* const* d_in, const int* in_sizes, int n_in,
                              void* d_out, int out_size, void* d_ws, size_t ws_size,
                              hipStream_t stream)
{
    const float* f  = (const float*)d_in[0];
    const float* s1 = (const float*)d_in[1];
    const float* s2 = (const float*)d_in[2];
    float* out  = (float*)d_out;
    float* bsum = (float*)d_ws;          // 3072 floats = 12 KB scratch

    const int N = in_sizes[0];           // 48 * 512 * 512
    const int planes = N / (WIDTH * HEIGHT);

    GW gw;
    double gd[11], gs = 0.0;
    for (int i = 0; i < 11; ++i) {
        double d = (double)(i - 5);
        gd[i] = exp(-(d * d) / 4.5);     // 2*sigma^2 = 4.5
        gs += gd[i];
    }
    for (int i = 0; i < 11; ++i) {
        gw.g[i] = (float)(gd[i] / gs);
        uint32_t h = f2h(gw.g[i]);
        gw.wpk[i] = (h << 16) | h;       // broadcast half2
    }

    dim3 grid(WIDTH / TSX, HEIGHT / TILE_H, planes);
    const int nb = (WIDTH / TSX) * (HEIGHT / TILE_H) * planes;
    ssim_tile<<<grid, dim3(256), 0, stream>>>(f, s1, s2, bsum, gw);
    ssim_final<<<1, dim3(256), 0, stream>>>(bsum, out, nb, 0.5f / (float)N);
}